// Round 2
// baseline (284.448 us; speedup 1.0000x reference)
//
#include <hip/hip_runtime.h>

#define N_NODES 25000
#define N_EDGES 400000
#define IN_CH 1024
#define FC 128
#define ADD_CH 20
#define XCH 148   // FC + ADD
#define MID 37
#define OUT_CH 3
#define MAXDEG 64

typedef short bf16x8 __attribute__((ext_vector_type(8)));
typedef float f32x4 __attribute__((ext_vector_type(4)));

__device__ __forceinline__ unsigned int f2bf(float x) {
    unsigned int u = __builtin_bit_cast(unsigned int, x);
    unsigned int lsb = (u >> 16) & 1u;
    u += 0x7fffu + lsb;           // round-to-nearest-even
    return u >> 16;
}
__device__ __forceinline__ unsigned int pkbf(float a, float b) {
    return f2bf(a) | (f2bf(b) << 16);
}
__device__ __forceinline__ float bflo(unsigned int v) {
    return __builtin_bit_cast(float, v << 16);
}
__device__ __forceinline__ float bfhi(unsigned int v) {
    return __builtin_bit_cast(float, v & 0xffff0000u);
}

// ---------------- prep: W swizzle + CSR build (cursor zeroed by memset) -----
// W frag layout: unit (chgrp, kt) = 64 lanes x 16 B contiguous; lane (q,l15)
// holds W[chgrp*16+l15][kt*32+q*8 .. +8] as bf16x8.
// Build blocks moved HERE (out of the GEMM dispatch): their 400K random
// cross-XCD atomics + 4B scatter stores were evicting the W working set from
// every XCD L2 during the GEMM K-loop (theory for MfmaUtil=6.5%).
#define WSWZ_B 16
#define BUILD_B 782   // ceil(400000/512)

__global__ __launch_bounds__(512) void prep_build(const float* __restrict__ Wl,
                                                  const float* __restrict__ Wr,
                                                  ushort* __restrict__ Wpk,
                                                  const int* __restrict__ edges,
                                                  int* __restrict__ cursor,
                                                  int* __restrict__ col) {
    int b = blockIdx.x, t = threadIdx.x;
    if (b < WSWZ_B) {
        int w = t >> 6, lane = t & 63, l15 = lane & 15, q8 = (lane >> 4) * 8;
        int ch = b * 16 + l15;
        const float* src = (ch < FC) ? (Wl + (size_t)ch * IN_CH)
                                     : (Wr + (size_t)(ch - FC) * IN_CH);
        #pragma unroll
        for (int j = 0; j < 4; ++j) {
            int kt = w * 4 + j;
            float4 lo = *(const float4*)(src + kt * 32 + q8);
            float4 hi = *(const float4*)(src + kt * 32 + q8 + 4);
            uint4 pk;
            pk.x = pkbf(lo.x, lo.y); pk.y = pkbf(lo.z, lo.w);
            pk.z = pkbf(hi.x, hi.y); pk.w = pkbf(hi.z, hi.w);
            ((uint4*)Wpk)[(size_t)(b * 32 + kt) * 64 + lane] = pk;
        }
    } else {
        int e = (b - WSWZ_B) * 512 + t;
        if (e < N_EDGES) {
            int dst = edges[N_EDGES + e];
            int pos = atomicAdd(&cursor[dst], 1);
            if (pos < MAXDEG) col[dst * MAXDEG + pos] = edges[e];
        }
    }
}

// ---------------- fused stage + GEMM (now a clean, GEMM-only dispatch) ------
// 512 thr = 8 waves, 32 nodes x 256 ch, 64 KB LDS F-frags.
//   Wave w = 32 ch (chgrps 2w,2w+1) x 32 nodes -> acc[2][2] = 16 VGPRs.
//   2 blocks/CU => 16 waves/CU = 4/SIMD.
#define GEMM_B 782    // ceil(25000/32)

__global__ __launch_bounds__(512, 4) void gemm(const float* __restrict__ A,
                                               const ushort* __restrict__ Wpk,
                                               ushort* __restrict__ Py,
                                               ushort* __restrict__ Pz) {
    __shared__ __align__(16) ushort Fs[2 * 32 * 64 * 8];   // 64 KB frag layout
    int b = blockIdx.x, t = threadIdx.x;
    int w = t >> 6, lane = t & 63;
    int l15 = lane & 15, q = lane >> 4;
    int m0 = b * 32;

    // ---- W pointers + prefetch of kt=0,1 fragments ----
    const bf16x8* W0 = (const bf16x8*)Wpk + (size_t)(w * 2 + 0) * 32 * 64 + lane;
    const bf16x8* W1 = (const bf16x8*)Wpk + (size_t)(w * 2 + 1) * 32 * 64 + lane;
    bf16x8 aw[2][2], an[2][2], bw[2][2], bn[2][2];
    aw[0][0] = W0[0];  aw[0][1] = W1[0];
    aw[1][0] = W0[64]; aw[1][1] = W1[64];

    // ---- stage 32 feature rows -> LDS frags (XOR-swizzled) ----
    {
        int r = t >> 4;            // row-in-tile 0..31
        int p0 = t & 15;           // position 0..15
        int row = m0 + r; if (row >= N_NODES) row = N_NODES - 1;
        const float* src = A + (size_t)row * IN_CH;
        int g = r >> 4, l = r & 15;
        #pragma unroll
        for (int h = 0; h < 2; ++h) {
            float4 lo[4], hi[4];
            #pragma unroll
            for (int m = 0; m < 4; ++m) {
                int o = (h * 4 + m) * 16 + p0;
                lo[m] = *(const float4*)(src + o * 8);
                hi[m] = *(const float4*)(src + o * 8 + 4);
            }
            #pragma unroll
            for (int m = 0; m < 4; ++m) {
                int o = (h * 4 + m) * 16 + p0;
                int kt = o >> 2, qq = o & 3;
                uint4 pk;
                pk.x = pkbf(lo[m].x, lo[m].y); pk.y = pkbf(lo[m].z, lo[m].w);
                pk.z = pkbf(hi[m].x, hi[m].y); pk.w = pkbf(hi[m].z, hi[m].w);
                int u = (g * 32 + kt) * 64 + qq * 16 + ((l + qq) & 15);
                *(uint4*)&Fs[(size_t)u * 8] = pk;
            }
        }
    }
    __syncthreads();

    int ru = q * 16 + ((l15 + q) & 15);     // swizzled read unit within kt-block
    const bf16x8* F0 = (const bf16x8*)Fs + ru;
    const bf16x8* F1 = (const bf16x8*)Fs + 32 * 64 + ru;

    f32x4 acc[2][2] = {};
    bw[0][0] = F0[0];  bw[0][1] = F1[0];
    bw[1][0] = F0[64]; bw[1][1] = F1[64];

    #pragma unroll
    for (int kt = 0; kt < 32; kt += 2) {
        int kn = kt + 2;
        if (kn < 32) {
            an[0][0] = W0[(size_t)kn * 64];       an[0][1] = W1[(size_t)kn * 64];
            an[1][0] = W0[(size_t)(kn + 1) * 64]; an[1][1] = W1[(size_t)(kn + 1) * 64];
            bn[0][0] = F0[(size_t)kn * 64];       bn[0][1] = F1[(size_t)kn * 64];
            bn[1][0] = F0[(size_t)(kn + 1) * 64]; bn[1][1] = F1[(size_t)(kn + 1) * 64];
        }
        #pragma unroll
        for (int j = 0; j < 2; ++j)
            #pragma unroll
            for (int cf = 0; cf < 2; ++cf) {
                acc[cf][0] = __builtin_amdgcn_mfma_f32_16x16x32_bf16(aw[j][cf], bw[j][0], acc[cf][0], 0, 0, 0);
                acc[cf][1] = __builtin_amdgcn_mfma_f32_16x16x32_bf16(aw[j][cf], bw[j][1], acc[cf][1], 0, 0, 0);
            }
        if (kn < 32) {
            #pragma unroll
            for (int j = 0; j < 2; ++j)
                #pragma unroll
                for (int cf = 0; cf < 2; ++cf) {
                    aw[j][cf] = an[j][cf];
                    bw[j][cf] = bn[j][cf];
                }
        }
    }
    // D layout: ch = w*32 + cf*16 + q*4 + reg, node = m0 + g*16 + l15
    #pragma unroll
    for (int g = 0; g < 2; ++g) {
        int node = m0 + g * 16 + l15;
        if (node < N_NODES) {
            ushort* base = (w < 4) ? (Py + (size_t)node * FC + w * 32)
                                   : (Pz + (size_t)node * FC + (w - 4) * 32);
            #pragma unroll
            for (int cf = 0; cf < 2; ++cf) {
                f32x4 v = acc[cf][g];
                uint2 pk;
                pk.x = pkbf(v[0], v[1]);
                pk.y = pkbf(v[2], v[3]);
                *(uint2*)(base + cf * 16 + q * 4) = pk;
            }
        }
    }
}

// ---------------- fused gather + SAGE combine + MLP tail (unchanged) --------
__global__ __launch_bounds__(256) void fused_tail(const ushort* __restrict__ Py,
                                                  const ushort* __restrict__ Pz,
                                                  const int* __restrict__ deg,
                                                  const int* __restrict__ col,
                                                  const float* __restrict__ addf,
                                                  const float* __restrict__ bl,
                                                  const float* __restrict__ W1,
                                                  const float* __restrict__ b1,
                                                  const float* __restrict__ W2,
                                                  const float* __restrict__ b2,
                                                  const float* __restrict__ gamma,
                                                  const float* __restrict__ beta,
                                                  const float* __restrict__ rmean,
                                                  const float* __restrict__ rvar,
                                                  float* __restrict__ out) {
    __shared__ float W1s[XCH][MID + 3];
    __shared__ float xbuf[4][XCH + 4];
    __shared__ float hbuf[4][MID + 3];
    int t = threadIdx.x;
    for (int idx = t; idx < MID * XCH; idx += 256) {
        int j = idx / XCH, k = idx - j * XCH;
        W1s[k][j] = W1[idx];
    }
    __syncthreads();
    int w = t >> 6, lane = t & 63;
    int n = blockIdx.x * 4 + w;
    bool valid = (n < N_NODES);
    int d = valid ? deg[n] : 0;
    if (d > MAXDEG) d = MAXDEG;
    int g = lane >> 4, c16 = lane & 15;
    float s[8] = {0.f, 0.f, 0.f, 0.f, 0.f, 0.f, 0.f, 0.f};
    if (d > 0) {
        int cidx = col[n * MAXDEG + (lane < d ? lane : 0)];
        for (int i = 0; i < d; i += 16) {
            int e[4];
            uint4 v[4];
            #pragma unroll
            for (int j = 0; j < 4; ++j) {
                int ee = i + g + j * 4;
                e[j] = __shfl(cidx, (ee < d) ? ee : 0);
            }
            #pragma unroll
            for (int j = 0; j < 4; ++j)
                v[j] = *(const uint4*)&Py[(size_t)e[j] * FC + c16 * 8];
            #pragma unroll
            for (int j = 0; j < 4; ++j) {
                if (i + g + j * 4 < d) {
                    s[0] += bflo(v[j].x); s[1] += bfhi(v[j].x);
                    s[2] += bflo(v[j].y); s[3] += bfhi(v[j].y);
                    s[4] += bflo(v[j].z); s[5] += bfhi(v[j].z);
                    s[6] += bflo(v[j].w); s[7] += bfhi(v[j].w);
                }
            }
        }
        #pragma unroll
        for (int r = 0; r < 8; ++r) {
            s[r] += __shfl_xor(s[r], 16);
            s[r] += __shfl_xor(s[r], 32);
        }
    }
    if (valid) {
        if (lane < 16) {
            #pragma unroll
            for (int r = 0; r < 8; ++r) xbuf[w][lane * 8 + r] = s[r];
        }
        float invd = 1.0f / (float)(d > 1 ? d : 1);
        unsigned int vr = *(const unsigned int*)&Pz[(size_t)n * FC + lane * 2];
        float x0 = xbuf[w][2 * lane] * invd + bl[2 * lane] + bflo(vr);
        float x1 = xbuf[w][2 * lane + 1] * invd + bl[2 * lane + 1] + bfhi(vr);
        x0 = (x0 >= 0.f) ? x0 : 0.01f * x0;
        x1 = (x1 >= 0.f) ? x1 : 0.01f * x1;
        xbuf[w][2 * lane] = x0;
        xbuf[w][2 * lane + 1] = x1;
        if (lane < ADD_CH) xbuf[w][FC + lane] = addf[(size_t)n * ADD_CH + lane];
        if (lane < MID) {
            float h = b1[lane];
            #pragma unroll 4
            for (int k = 0; k < XCH; ++k) h += W1s[k][lane] * xbuf[w][k];
            h = fmaxf(h, 0.0f);
            h = gamma[lane] * (h - rmean[lane]) * rsqrtf(rvar[lane] + 1e-5f) + beta[lane];
            hbuf[w][lane] = h;
        }
        if (lane < OUT_CH) {
            float o = b2[lane];
            #pragma unroll
            for (int j = 0; j < MID; ++j) o += W2[lane * MID + j] * hbuf[w][j];
            out[(size_t)n * OUT_CH + lane] = o;
        }
    }
}

// ---------------- launch ----------------

extern "C" void kernel_launch(void* const* d_in, const int* in_sizes, int n_in,
                              void* d_out, int out_size, void* d_ws, size_t ws_size,
                              hipStream_t stream) {
    const float* features = (const float*)d_in[0];
    const int*   edges    = (const int*)d_in[1];
    const float* addf     = (const float*)d_in[4];
    const float* Wl       = (const float*)d_in[5];
    const float* bl       = (const float*)d_in[6];
    const float* Wr       = (const float*)d_in[7];
    const float* W1       = (const float*)d_in[8];
    const float* b1       = (const float*)d_in[9];
    const float* W2       = (const float*)d_in[10];
    const float* b2       = (const float*)d_in[11];
    const float* gamma    = (const float*)d_in[12];
    const float* beta     = (const float*)d_in[13];
    const float* rmean    = (const float*)d_in[14];
    const float* rvar     = (const float*)d_in[15];
    float* out = (float*)d_out;

    char* ws = (char*)d_ws;
    size_t off = 0;
    ushort* Py = (ushort*)(ws + off);     off += (size_t)N_NODES * FC * 2;        // 6.4 MB
    ushort* Pz = (ushort*)(ws + off);     off += (size_t)N_NODES * FC * 2;        // 6.4 MB
    ushort* Wpk = (ushort*)(ws + off);    off += (size_t)16 * 32 * 64 * 16;       // 512 KB
    int* cursor = (int*)(ws + off);       off += (size_t)N_NODES * 4;             // 100 KB
    int* col = (int*)(ws + off);          off += (size_t)N_NODES * MAXDEG * 4;    // 6.4 MB

    hipMemsetAsync(cursor, 0, (size_t)N_NODES * 4, stream);

    prep_build<<<WSWZ_B + BUILD_B, 512, 0, stream>>>(Wl, Wr, Wpk, edges, cursor, col);

    gemm<<<GEMM_B, 512, 0, stream>>>(features, Wpk, Py, Pz);

    fused_tail<<<(N_NODES + 3) / 4, 256, 0, stream>>>(Py, Pz, cursor, col, addf, bl,
                                                      W1, b1, W2, b2, gamma, beta,
                                                      rmean, rvar, out);
}

// Round 3
// 273.454 us; speedup vs baseline: 1.0402x; 1.0402x over previous
//
#include <hip/hip_runtime.h>

#define N_NODES 25000
#define N_EDGES 400000
#define IN_CH 1024
#define FC 128
#define ADD_CH 20
#define XCH 148   // FC + ADD
#define MID 37
#define OUT_CH 3
#define MAXDEG 64

typedef short bf16x8 __attribute__((ext_vector_type(8)));
typedef float f32x4 __attribute__((ext_vector_type(4)));

__device__ __forceinline__ unsigned int f2bf(float x) {
    unsigned int u = __builtin_bit_cast(unsigned int, x);
    unsigned int lsb = (u >> 16) & 1u;
    u += 0x7fffu + lsb;           // round-to-nearest-even
    return u >> 16;
}
__device__ __forceinline__ unsigned int pkbf(float a, float b) {
    return f2bf(a) | (f2bf(b) << 16);
}
__device__ __forceinline__ float bflo(unsigned int v) {
    return __builtin_bit_cast(float, v << 16);
}
__device__ __forceinline__ float bfhi(unsigned int v) {
    return __builtin_bit_cast(float, v & 0xffff0000u);
}

// async 16B global->LDS DMA (counts in vmcnt; drained by __syncthreads)
__device__ __forceinline__ void gload16(const void* g, void* l) {
    __builtin_amdgcn_global_load_lds(
        (const __attribute__((address_space(1))) unsigned int*)g,
        (__attribute__((address_space(3))) unsigned int*)l,
        16, 0, 0);
}

// ---------------- prep: W swizzle + CSR build (cursor zeroed by memset) -----
// NEW Wpk layout: [kt(32)][chgrp(16)][lane(64)] x 16B, so one K-chunk (one kt)
// of all 256 channels is a CONTIGUOUS 16 KB slab -> linear global_load_lds.
// lane (q,l15) of unit (kt,chgrp) holds W[chgrp*16+l15][kt*32+q*8 .. +8] bf16x8.
#define WSWZ_B 16
#define BUILD_B 782   // ceil(400000/512)

__global__ __launch_bounds__(512) void prep_build(const float* __restrict__ Wl,
                                                  const float* __restrict__ Wr,
                                                  ushort* __restrict__ Wpk,
                                                  const int* __restrict__ edges,
                                                  int* __restrict__ cursor,
                                                  int* __restrict__ col) {
    int b = blockIdx.x, t = threadIdx.x;
    if (b < WSWZ_B) {
        int w = t >> 6, lane = t & 63, l15 = lane & 15, q8 = (lane >> 4) * 8;
        int ch = b * 16 + l15;
        const float* src = (ch < FC) ? (Wl + (size_t)ch * IN_CH)
                                     : (Wr + (size_t)(ch - FC) * IN_CH);
        #pragma unroll
        for (int j = 0; j < 4; ++j) {
            int kt = w * 4 + j;
            float4 lo = *(const float4*)(src + kt * 32 + q8);
            float4 hi = *(const float4*)(src + kt * 32 + q8 + 4);
            uint4 pk;
            pk.x = pkbf(lo.x, lo.y); pk.y = pkbf(lo.z, lo.w);
            pk.z = pkbf(hi.x, hi.y); pk.w = pkbf(hi.z, hi.w);
            ((uint4*)Wpk)[((size_t)kt * 16 + b) * 64 + lane] = pk;
        }
    } else {
        int e = (b - WSWZ_B) * 512 + t;
        if (e < N_EDGES) {
            int dst = edges[N_EDGES + e];
            int pos = atomicAdd(&cursor[dst], 1);
            if (pos < MAXDEG) col[dst * MAXDEG + pos] = edges[e];
        }
    }
}

// ---------------- GEMM v3: structural pipeline via global_load_lds ----------
// Rounds 0-2 evidence: compiler collapses register pipelines (VGPR stuck at
// 52, loads sunk to use, MfmaUtil 6.5-7.7%). Fix = m97 structure: async
// global->LDS DMA double-buffered, drain at barrier, 3 blocks/CU TLP.
//   Tile: M=64 nodes x N=256 ch, K chunks of 32 (1 kt each), 32 chunks.
//   LDS/chunk: W bf16 16 KB (1024 slots) + A f32 8 KB (512 slots); dbuf 48 KB.
//   8 waves as (wm 0..1, wn 0..3): wave = 64ch x 32n -> acc[4][2] (32 VGPR).
//   Per chunk/wave: 2+1 gload16 (stage next), 4+4 ds_read_b128, 8 cvt, 8 MFMA.
//   A staged f32 (features read directly, no convert pass), cvt to bf16 in
//   VALU after LDS read (8 pkbf/chunk/wave - negligible).
// A-LDS slot s: g=s>>7, hq=(s>>6)&1, l=s&63 (q=l>>4,l15=l&15) holds
//   features[m0+g*16+l15][c*32 + q*8 + hq*4 .. +4]  (16B, frag-contiguous).
#define GEMM_B 391    // ceil(25000/64)

__global__ __launch_bounds__(512, 6) void gemm(const float* __restrict__ A,
                                               const ushort* __restrict__ Wpk,
                                               ushort* __restrict__ Py,
                                               ushort* __restrict__ Pz) {
    __shared__ uint4 LDS[2][1536];   // [buf][ 0..1023 = W | 1024..1535 = A ]
    int t = threadIdx.x;
    int b = blockIdx.x;
    int m0 = b * 64;

    // per-thread A staging source (fixed per thread; +c*32 floats per chunk)
    int ga = t >> 7, hq = (t >> 6) & 1, la = t & 63;
    int nodeA = m0 + ga * 16 + (la & 15);
    if (nodeA >= N_NODES) nodeA = N_NODES - 1;
    const float* Asrc = A + (size_t)nodeA * IN_CH + (la >> 4) * 8 + hq * 4;
    const uint4* Wg = (const uint4*)Wpk;
    int tb = t & ~63;                 // wave-uniform slot base

    int w = t >> 6, lane = t & 63;
    int wm = w >> 2, wn = w & 3;
    int l15 = lane & 15, q = lane >> 4;

    f32x4 acc[4][2] = {};

    // prologue: stage chunk 0 into buf 0
    {
        const uint4* ws = Wg;
        gload16(ws + t,        &LDS[0][tb]);
        gload16(ws + 512 + t,  &LDS[0][512 + tb]);
        gload16(Asrc,          &LDS[0][1024 + tb]);
    }
    __syncthreads();

    for (int c = 0; c < 32; ++c) {
        int cur = c & 1;
        if (c + 1 < 32) {             // stage next chunk (async, drains at barrier)
            const uint4* ws = Wg + (size_t)(c + 1) * 1024;
            gload16(ws + t,       &LDS[cur ^ 1][tb]);
            gload16(ws + 512 + t, &LDS[cur ^ 1][512 + tb]);
            gload16(Asrc + (size_t)(c + 1) * 32, &LDS[cur ^ 1][1024 + tb]);
        }
        // ds-read W frags (contiguous 64-lane x 16B units: conflict-free)
        bf16x8 wf[4];
        #pragma unroll
        for (int i = 0; i < 4; ++i)
            wf[i] = *(const bf16x8*)&LDS[cur][(wn * 4 + i) * 64 + lane];
        // ds-read A frags (f32) + convert to bf16
        bf16x8 af[2];
        #pragma unroll
        for (int g2 = 0; g2 < 2; ++g2) {
            f32x4 lo = *(const f32x4*)&LDS[cur][1024 + ((wm * 2 + g2) * 2 + 0) * 64 + lane];
            f32x4 hi = *(const f32x4*)&LDS[cur][1024 + ((wm * 2 + g2) * 2 + 1) * 64 + lane];
            uint4 pk;
            pk.x = pkbf(lo[0], lo[1]); pk.y = pkbf(lo[2], lo[3]);
            pk.z = pkbf(hi[0], hi[1]); pk.w = pkbf(hi[2], hi[3]);
            af[g2] = __builtin_bit_cast(bf16x8, pk);
        }
        #pragma unroll
        for (int i = 0; i < 4; ++i)
            #pragma unroll
            for (int g2 = 0; g2 < 2; ++g2)
                acc[i][g2] = __builtin_amdgcn_mfma_f32_16x16x32_bf16(wf[i], af[g2], acc[i][g2], 0, 0, 0);
        __syncthreads();              // drains vmcnt (next stage) + lgkm + barrier
    }

    // D layout: ch = wn*64 + i*16 + q*4 + reg, node = m0 + wm*32 + g2*16 + l15
    #pragma unroll
    for (int g2 = 0; g2 < 2; ++g2) {
        int node = m0 + wm * 32 + g2 * 16 + l15;
        if (node < N_NODES) {
            ushort* base = (wn < 2) ? (Py + (size_t)node * FC + (wn & 1) * 64 + q * 4)
                                    : (Pz + (size_t)node * FC + (wn & 1) * 64 + q * 4);
            #pragma unroll
            for (int i = 0; i < 4; ++i) {
                f32x4 v = acc[i][g2];
                uint2 pk;
                pk.x = pkbf(v[0], v[1]);
                pk.y = pkbf(v[2], v[3]);
                *(uint2*)(base + i * 16) = pk;
            }
        }
    }
}

// ---------------- fused gather + SAGE combine + MLP tail (unchanged) --------
__global__ __launch_bounds__(256) void fused_tail(const ushort* __restrict__ Py,
                                                  const ushort* __restrict__ Pz,
                                                  const int* __restrict__ deg,
                                                  const int* __restrict__ col,
                                                  const float* __restrict__ addf,
                                                  const float* __restrict__ bl,
                                                  const float* __restrict__ W1,
                                                  const float* __restrict__ b1,
                                                  const float* __restrict__ W2,
                                                  const float* __restrict__ b2,
                                                  const float* __restrict__ gamma,
                                                  const float* __restrict__ beta,
                                                  const float* __restrict__ rmean,
                                                  const float* __restrict__ rvar,
                                                  float* __restrict__ out) {
    __shared__ float W1s[XCH][MID + 3];
    __shared__ float xbuf[4][XCH + 4];
    __shared__ float hbuf[4][MID + 3];
    int t = threadIdx.x;
    for (int idx = t; idx < MID * XCH; idx += 256) {
        int j = idx / XCH, k = idx - j * XCH;
        W1s[k][j] = W1[idx];
    }
    __syncthreads();
    int w = t >> 6, lane = t & 63;
    int n = blockIdx.x * 4 + w;
    bool valid = (n < N_NODES);
    int d = valid ? deg[n] : 0;
    if (d > MAXDEG) d = MAXDEG;
    int g = lane >> 4, c16 = lane & 15;
    float s[8] = {0.f, 0.f, 0.f, 0.f, 0.f, 0.f, 0.f, 0.f};
    if (d > 0) {
        int cidx = col[n * MAXDEG + (lane < d ? lane : 0)];
        for (int i = 0; i < d; i += 16) {
            int e[4];
            uint4 v[4];
            #pragma unroll
            for (int j = 0; j < 4; ++j) {
                int ee = i + g + j * 4;
                e[j] = __shfl(cidx, (ee < d) ? ee : 0);
            }
            #pragma unroll
            for (int j = 0; j < 4; ++j)
                v[j] = *(const uint4*)&Py[(size_t)e[j] * FC + c16 * 8];
            #pragma unroll
            for (int j = 0; j < 4; ++j) {
                if (i + g + j * 4 < d) {
                    s[0] += bflo(v[j].x); s[1] += bfhi(v[j].x);
                    s[2] += bflo(v[j].y); s[3] += bfhi(v[j].y);
                    s[4] += bflo(v[j].z); s[5] += bfhi(v[j].z);
                    s[6] += bflo(v[j].w); s[7] += bfhi(v[j].w);
                }
            }
        }
        #pragma unroll
        for (int r = 0; r < 8; ++r) {
            s[r] += __shfl_xor(s[r], 16);
            s[r] += __shfl_xor(s[r], 32);
        }
    }
    if (valid) {
        if (lane < 16) {
            #pragma unroll
            for (int r = 0; r < 8; ++r) xbuf[w][lane * 8 + r] = s[r];
        }
        float invd = 1.0f / (float)(d > 1 ? d : 1);
        unsigned int vr = *(const unsigned int*)&Pz[(size_t)n * FC + lane * 2];
        float x0 = xbuf[w][2 * lane] * invd + bl[2 * lane] + bflo(vr);
        float x1 = xbuf[w][2 * lane + 1] * invd + bl[2 * lane + 1] + bfhi(vr);
        x0 = (x0 >= 0.f) ? x0 : 0.01f * x0;
        x1 = (x1 >= 0.f) ? x1 : 0.01f * x1;
        xbuf[w][2 * lane] = x0;
        xbuf[w][2 * lane + 1] = x1;
        if (lane < ADD_CH) xbuf[w][FC + lane] = addf[(size_t)n * ADD_CH + lane];
        if (lane < MID) {
            float h = b1[lane];
            #pragma unroll 4
            for (int k = 0; k < XCH; ++k) h += W1s[k][lane] * xbuf[w][k];
            h = fmaxf(h, 0.0f);
            h = gamma[lane] * (h - rmean[lane]) * rsqrtf(rvar[lane] + 1e-5f) + beta[lane];
            hbuf[w][lane] = h;
        }
        if (lane < OUT_CH) {
            float o = b2[lane];
            #pragma unroll
            for (int j = 0; j < MID; ++j) o += W2[lane * MID + j] * hbuf[w][j];
            out[(size_t)n * OUT_CH + lane] = o;
        }
    }
}

// ---------------- launch ----------------

extern "C" void kernel_launch(void* const* d_in, const int* in_sizes, int n_in,
                              void* d_out, int out_size, void* d_ws, size_t ws_size,
                              hipStream_t stream) {
    const float* features = (const float*)d_in[0];
    const int*   edges    = (const int*)d_in[1];
    const float* addf     = (const float*)d_in[4];
    const float* Wl       = (const float*)d_in[5];
    const float* bl       = (const float*)d_in[6];
    const float* Wr       = (const float*)d_in[7];
    const float* W1       = (const float*)d_in[8];
    const float* b1       = (const float*)d_in[9];
    const float* W2       = (const float*)d_in[10];
    const float* b2       = (const float*)d_in[11];
    const float* gamma    = (const float*)d_in[12];
    const float* beta     = (const float*)d_in[13];
    const float* rmean    = (const float*)d_in[14];
    const float* rvar     = (const float*)d_in[15];
    float* out = (float*)d_out;

    char* ws = (char*)d_ws;
    size_t off = 0;
    ushort* Py = (ushort*)(ws + off);     off += (size_t)N_NODES * FC * 2;        // 6.4 MB
    ushort* Pz = (ushort*)(ws + off);     off += (size_t)N_NODES * FC * 2;        // 6.4 MB
    ushort* Wpk = (ushort*)(ws + off);    off += (size_t)32 * 16 * 64 * 16;       // 512 KB
    int* cursor = (int*)(ws + off);       off += (size_t)N_NODES * 4;             // 100 KB
    int* col = (int*)(ws + off);          off += (size_t)N_NODES * MAXDEG * 4;    // 6.4 MB

    hipMemsetAsync(cursor, 0, (size_t)N_NODES * 4, stream);

    prep_build<<<WSWZ_B + BUILD_B, 512, 0, stream>>>(Wl, Wr, Wpk, edges, cursor, col);

    gemm<<<GEMM_B, 512, 0, stream>>>(features, Wpk, Py, Pz);

    fused_tail<<<(N_NODES + 3) / 4, 256, 0, stream>>>(Py, Pz, cursor, col, addf, bl,
                                                      W1, b1, W2, b2, gamma, beta,
                                                      rmean, rvar, out);
}

// Round 4
// 268.398 us; speedup vs baseline: 1.0598x; 1.0188x over previous
//
#include <hip/hip_runtime.h>

#define N_NODES 25000
#define N_EDGES 400000
#define IN_CH 1024
#define FC 128
#define ADD_CH 20
#define XCH 148   // FC + ADD
#define MID 37
#define OUT_CH 3
#define MAXDEG 64

typedef short bf16x8 __attribute__((ext_vector_type(8)));
typedef float f32x4 __attribute__((ext_vector_type(4)));

__device__ __forceinline__ float bflo(unsigned int v) {
    return __builtin_bit_cast(float, v << 16);
}
__device__ __forceinline__ float bfhi(unsigned int v) {
    return __builtin_bit_cast(float, v & 0xffff0000u);
}
// pack 2 f32 -> 2 bf16 (RNE), single VALU op (was ~9 ops of bit-twiddle)
__device__ __forceinline__ unsigned int cvtpk(float a, float b) {
    unsigned int r;
    asm("v_cvt_pk_bf16_f32 %0, %1, %2" : "=v"(r) : "v"(a), "v"(b));
    return r;
}

// async 16B global->LDS DMA (counts in vmcnt; drained by __syncthreads)
__device__ __forceinline__ void gload16(const void* g, void* l) {
    __builtin_amdgcn_global_load_lds(
        (const __attribute__((address_space(1))) unsigned int*)g,
        (__attribute__((address_space(3))) unsigned int*)l,
        16, 0, 0);
}

// ---------------- prep: W swizzle + cursor zero (one dispatch) --------------
// Wpk layout: [kt(32)][chgrp(16)][lane(64)] x 16B -> one K-chunk (one kt) of
// all 256 channels is a CONTIGUOUS 16 KB slab for linear global_load_lds.
// lane (q,l15) of unit (kt,chgrp) holds W[chgrp*16+l15][kt*32+q*8 .. +8] bf16x8.
#define WSWZ_B 16
#define ZERO_B 49   // 49*512 >= 25000

__global__ __launch_bounds__(512) void prep(const float* __restrict__ Wl,
                                            const float* __restrict__ Wr,
                                            ushort* __restrict__ Wpk,
                                            int* __restrict__ cursor) {
    int b = blockIdx.x, t = threadIdx.x;
    if (b < WSWZ_B) {
        int w = t >> 6, lane = t & 63, l15 = lane & 15, q8 = (lane >> 4) * 8;
        int ch = b * 16 + l15;
        const float* src = (ch < FC) ? (Wl + (size_t)ch * IN_CH)
                                     : (Wr + (size_t)(ch - FC) * IN_CH);
        #pragma unroll
        for (int j = 0; j < 4; ++j) {
            int kt = w * 4 + j;
            float4 lo = *(const float4*)(src + kt * 32 + q8);
            float4 hi = *(const float4*)(src + kt * 32 + q8 + 4);
            uint4 pk;
            pk.x = cvtpk(lo.x, lo.y); pk.y = cvtpk(lo.z, lo.w);
            pk.z = cvtpk(hi.x, hi.y); pk.w = cvtpk(hi.z, hi.w);
            ((uint4*)Wpk)[((size_t)kt * 16 + b) * 64 + lane] = pk;
        }
    } else {
        int i = (b - WSWZ_B) * 512 + t;
        if (i < N_NODES) cursor[i] = 0;
    }
}

// ---------------- hetero: pipelined GEMM + CSR build off critical path ------
// GEMM (m97 structure, round-3, two fixes):
//   * launch_bounds (512,4): round-3's (512,6) capped VGPR at ~85 < the ~95
//     the pipeline needs -> suspected spill-to-scratch in the K-loop.
//     Grid is 391 blocks (1.5/CU) so 3-block co-residency bought nothing.
//   * v_cvt_pk_bf16_f32 for the A f32->bf16 convert: the hand-rolled RNE was
//     ~150 VALU cyc/chunk/wave vs 39 MFMA cyc (conversion-bound inner loop).
//   Tile: M=64 nodes x N=256 ch, 32 K-chunks of 32. LDS dbuf 48 KB.
//   8 waves (wm 0..1, wn 0..3): wave = 64ch x 32n -> acc[4][2].
// Build rides along (blocks after GEMM_B), round-0 style: serializing it in
// rounds 2-3 cost ~25 us of critical path; gemm's latency is now structurally
// hidden so L2 pollution from the atomics is the lesser evil.
#define GEMM_B 391    // ceil(25000/64)
#define BUILD_B 782   // ceil(400000/512)

__global__ __launch_bounds__(512, 4) void gemm_build(const float* __restrict__ A,
                                                     const ushort* __restrict__ Wpk,
                                                     ushort* __restrict__ Py,
                                                     ushort* __restrict__ Pz,
                                                     const int* __restrict__ edges,
                                                     int* __restrict__ cursor,
                                                     int* __restrict__ col) {
    __shared__ uint4 LDS[2][1536];   // [buf][ 0..1023 = W | 1024..1535 = A ]
    int b = blockIdx.x, t = threadIdx.x;
    if (b >= GEMM_B) {
        int e = (b - GEMM_B) * 512 + t;
        if (e < N_EDGES) {
            int dst = edges[N_EDGES + e];
            int pos = atomicAdd(&cursor[dst], 1);
            if (pos < MAXDEG) col[dst * MAXDEG + pos] = edges[e];
        }
        return;
    }
    int m0 = b * 64;

    // per-thread A staging source (fixed per thread; +c*32 floats per chunk)
    int ga = t >> 7, hq = (t >> 6) & 1, la = t & 63;
    int nodeA = m0 + ga * 16 + (la & 15);
    if (nodeA >= N_NODES) nodeA = N_NODES - 1;
    const float* Asrc = A + (size_t)nodeA * IN_CH + (la >> 4) * 8 + hq * 4;
    const uint4* Wg = (const uint4*)Wpk;
    int tb = t & ~63;                 // wave-uniform LDS slot base

    int w = t >> 6, lane = t & 63;
    int wm = w >> 2, wn = w & 3;
    int l15 = lane & 15, q = lane >> 4;

    f32x4 acc[4][2] = {};

    // prologue: stage chunk 0 into buf 0
    gload16(Wg + t,       &LDS[0][tb]);
    gload16(Wg + 512 + t, &LDS[0][512 + tb]);
    gload16(Asrc,         &LDS[0][1024 + tb]);
    __syncthreads();

    for (int c = 0; c < 32; ++c) {
        int cur = c & 1;
        if (c + 1 < 32) {             // stage next chunk (async, drains at barrier)
            const uint4* ws = Wg + (size_t)(c + 1) * 1024;
            gload16(ws + t,       &LDS[cur ^ 1][tb]);
            gload16(ws + 512 + t, &LDS[cur ^ 1][512 + tb]);
            gload16(Asrc + (size_t)(c + 1) * 32, &LDS[cur ^ 1][1024 + tb]);
        }
        // ds-read W frags (contiguous 64-lane x 16B units: conflict-free)
        bf16x8 wf[4];
        #pragma unroll
        for (int i = 0; i < 4; ++i)
            wf[i] = *(const bf16x8*)&LDS[cur][(wn * 4 + i) * 64 + lane];
        // ds-read A frags (f32) + pack to bf16 via v_cvt_pk_bf16_f32
        bf16x8 af[2];
        #pragma unroll
        for (int g2 = 0; g2 < 2; ++g2) {
            f32x4 lo = *(const f32x4*)&LDS[cur][1024 + ((wm * 2 + g2) * 2 + 0) * 64 + lane];
            f32x4 hi = *(const f32x4*)&LDS[cur][1024 + ((wm * 2 + g2) * 2 + 1) * 64 + lane];
            uint4 pk;
            pk.x = cvtpk(lo[0], lo[1]); pk.y = cvtpk(lo[2], lo[3]);
            pk.z = cvtpk(hi[0], hi[1]); pk.w = cvtpk(hi[2], hi[3]);
            af[g2] = __builtin_bit_cast(bf16x8, pk);
        }
        #pragma unroll
        for (int i = 0; i < 4; ++i)
            #pragma unroll
            for (int g2 = 0; g2 < 2; ++g2)
                acc[i][g2] = __builtin_amdgcn_mfma_f32_16x16x32_bf16(wf[i], af[g2], acc[i][g2], 0, 0, 0);
        __syncthreads();              // drains vmcnt (next stage) + lgkm + barrier
    }

    // D layout: ch = wn*64 + i*16 + q*4 + reg, node = m0 + wm*32 + g2*16 + l15
    #pragma unroll
    for (int g2 = 0; g2 < 2; ++g2) {
        int node = m0 + wm * 32 + g2 * 16 + l15;
        if (node < N_NODES) {
            ushort* base = (wn < 2) ? (Py + (size_t)node * FC + (wn & 1) * 64 + q * 4)
                                    : (Pz + (size_t)node * FC + (wn & 1) * 64 + q * 4);
            #pragma unroll
            for (int i = 0; i < 4; ++i) {
                f32x4 v = acc[i][g2];
                uint2 pk;
                pk.x = cvtpk(v[0], v[1]);
                pk.y = cvtpk(v[2], v[3]);
                *(uint2*)(base + i * 16) = pk;
            }
        }
    }
}

// ---------------- fused gather + SAGE combine + MLP tail (8 nodes/block) ----
// 8 nodes/block @512 thr: halves the per-node share of the W1s LDS fill
// (5476 floats/block) and per-block fixed overhead vs 4 nodes @256.
__global__ __launch_bounds__(512) void fused_tail(const ushort* __restrict__ Py,
                                                  const ushort* __restrict__ Pz,
                                                  const int* __restrict__ deg,
                                                  const int* __restrict__ col,
                                                  const float* __restrict__ addf,
                                                  const float* __restrict__ bl,
                                                  const float* __restrict__ W1,
                                                  const float* __restrict__ b1,
                                                  const float* __restrict__ W2,
                                                  const float* __restrict__ b2,
                                                  const float* __restrict__ gamma,
                                                  const float* __restrict__ beta,
                                                  const float* __restrict__ rmean,
                                                  const float* __restrict__ rvar,
                                                  float* __restrict__ out) {
    __shared__ float W1s[XCH][MID + 3];
    __shared__ float xbuf[8][XCH + 4];
    __shared__ float hbuf[8][MID + 3];
    int t = threadIdx.x;
    for (int idx = t; idx < MID * XCH; idx += 512) {
        int j = idx / XCH, k = idx - j * XCH;
        W1s[k][j] = W1[idx];
    }
    __syncthreads();
    int w = t >> 6, lane = t & 63;
    int n = blockIdx.x * 8 + w;
    bool valid = (n < N_NODES);
    int d = valid ? deg[n] : 0;
    if (d > MAXDEG) d = MAXDEG;
    int g = lane >> 4, c16 = lane & 15;
    float s[8] = {0.f, 0.f, 0.f, 0.f, 0.f, 0.f, 0.f, 0.f};
    if (d > 0) {
        int cidx = col[n * MAXDEG + (lane < d ? lane : 0)];
        for (int i = 0; i < d; i += 16) {
            int e[4];
            uint4 v[4];
            #pragma unroll
            for (int j = 0; j < 4; ++j) {
                int ee = i + g + j * 4;
                e[j] = __shfl(cidx, (ee < d) ? ee : 0);
            }
            #pragma unroll
            for (int j = 0; j < 4; ++j)
                v[j] = *(const uint4*)&Py[(size_t)e[j] * FC + c16 * 8];
            #pragma unroll
            for (int j = 0; j < 4; ++j) {
                if (i + g + j * 4 < d) {
                    s[0] += bflo(v[j].x); s[1] += bfhi(v[j].x);
                    s[2] += bflo(v[j].y); s[3] += bfhi(v[j].y);
                    s[4] += bflo(v[j].z); s[5] += bfhi(v[j].z);
                    s[6] += bflo(v[j].w); s[7] += bfhi(v[j].w);
                }
            }
        }
        #pragma unroll
        for (int r = 0; r < 8; ++r) {
            s[r] += __shfl_xor(s[r], 16);
            s[r] += __shfl_xor(s[r], 32);
        }
    }
    if (valid) {
        if (lane < 16) {
            #pragma unroll
            for (int r = 0; r < 8; ++r) xbuf[w][lane * 8 + r] = s[r];
        }
        float invd = 1.0f / (float)(d > 1 ? d : 1);
        unsigned int vr = *(const unsigned int*)&Pz[(size_t)n * FC + lane * 2];
        float x0 = xbuf[w][2 * lane] * invd + bl[2 * lane] + bflo(vr);
        float x1 = xbuf[w][2 * lane + 1] * invd + bl[2 * lane + 1] + bfhi(vr);
        x0 = (x0 >= 0.f) ? x0 : 0.01f * x0;
        x1 = (x1 >= 0.f) ? x1 : 0.01f * x1;
        xbuf[w][2 * lane] = x0;
        xbuf[w][2 * lane + 1] = x1;
        if (lane < ADD_CH) xbuf[w][FC + lane] = addf[(size_t)n * ADD_CH + lane];
        if (lane < MID) {
            float h = b1[lane];
            #pragma unroll 4
            for (int k = 0; k < XCH; ++k) h += W1s[k][lane] * xbuf[w][k];
            h = fmaxf(h, 0.0f);
            h = gamma[lane] * (h - rmean[lane]) * rsqrtf(rvar[lane] + 1e-5f) + beta[lane];
            hbuf[w][lane] = h;
        }
        if (lane < OUT_CH) {
            float o = b2[lane];
            #pragma unroll
            for (int j = 0; j < MID; ++j) o += W2[lane * MID + j] * hbuf[w][j];
            out[(size_t)n * OUT_CH + lane] = o;
        }
    }
}

// ---------------- launch ----------------

extern "C" void kernel_launch(void* const* d_in, const int* in_sizes, int n_in,
                              void* d_out, int out_size, void* d_ws, size_t ws_size,
                              hipStream_t stream) {
    const float* features = (const float*)d_in[0];
    const int*   edges    = (const int*)d_in[1];
    const float* addf     = (const float*)d_in[4];
    const float* Wl       = (const float*)d_in[5];
    const float* bl       = (const float*)d_in[6];
    const float* Wr       = (const float*)d_in[7];
    const float* W1       = (const float*)d_in[8];
    const float* b1       = (const float*)d_in[9];
    const float* W2       = (const float*)d_in[10];
    const float* b2       = (const float*)d_in[11];
    const float* gamma    = (const float*)d_in[12];
    const float* beta     = (const float*)d_in[13];
    const float* rmean    = (const float*)d_in[14];
    const float* rvar     = (const float*)d_in[15];
    float* out = (float*)d_out;

    char* ws = (char*)d_ws;
    size_t off = 0;
    ushort* Py = (ushort*)(ws + off);     off += (size_t)N_NODES * FC * 2;        // 6.4 MB
    ushort* Pz = (ushort*)(ws + off);     off += (size_t)N_NODES * FC * 2;        // 6.4 MB
    ushort* Wpk = (ushort*)(ws + off);    off += (size_t)32 * 16 * 64 * 16;       // 512 KB
    int* cursor = (int*)(ws + off);       off += (size_t)N_NODES * 4;             // 100 KB
    int* col = (int*)(ws + off);          off += (size_t)N_NODES * MAXDEG * 4;    // 6.4 MB

    prep<<<WSWZ_B + ZERO_B, 512, 0, stream>>>(Wl, Wr, Wpk, cursor);

    gemm_build<<<GEMM_B + BUILD_B, 512, 0, stream>>>(features, Wpk, Py, Pz,
                                                     edges, cursor, col);

    fused_tail<<<(N_NODES + 7) / 8, 512, 0, stream>>>(Py, Pz, cursor, col, addf, bl,
                                                      W1, b1, W2, b2, gamma, beta,
                                                      rmean, rvar, out);
}